// Round 2
// baseline (1242.267 us; speedup 1.0000x reference)
//
#include <hip/hip_runtime.h>
#include <hip/hip_bf16.h>

#define NN 10000
#define NE 50000
#define FIN 40
#define FE 10
// L = 64

typedef float f32x4 __attribute__((ext_vector_type(4)));
typedef short s16x8 __attribute__((ext_vector_type(8)));

__device__ __forceinline__ float bcast(float v, int lane) {
    return __uint_as_float(__builtin_amdgcn_readlane(__float_as_uint(v), lane));
}
__device__ __forceinline__ ushort f2bf(float f) {
    uint u = __float_as_uint(f);
    uint r = (u + 0x7FFFu + ((u >> 16) & 1u)) >> 16;
    return (ushort)r;
}
__device__ __forceinline__ float bf2f(ushort h) {
    return __uint_as_float(((uint)h) << 16);
}

// ---------------- CSR build ----------------
__global__ void k_count(const int* __restrict__ ei, int* __restrict__ deg) {
    int e = blockIdx.x * 256 + threadIdx.x;
    if (e < NE) atomicAdd(&deg[ei[NE + e]], 1);
}

__global__ __launch_bounds__(1024) void k_scan(const int* __restrict__ deg,
                                               int* __restrict__ rowp,
                                               int* __restrict__ fill,
                                               float* __restrict__ invd) {
    __shared__ int wsum[16];
    __shared__ int chunkbase;
    int tid = threadIdx.x, lane = tid & 63, wv = tid >> 6;
    if (tid == 0) chunkbase = 0;
    __syncthreads();
    for (int base = 0; base < NN; base += 1024) {
        int idx = base + tid;
        int v = (idx < NN) ? deg[idx] : 0;
        int s = v;
#pragma unroll
        for (int off = 1; off < 64; off <<= 1) {
            int t = __shfl_up(s, off, 64);
            if (lane >= off) s += t;
        }
        if (lane == 63) wsum[wv] = s;
        __syncthreads();
        int carry = chunkbase;
        if (wv == 0 && lane < 16) {
            int x = wsum[lane];
#pragma unroll
            for (int off = 1; off < 16; off <<= 1) {
                int t = __shfl_up(x, off, 64);
                if (lane >= off) x += t;
            }
            wsum[lane] = x;  // inclusive over waves
        }
        __syncthreads();
        int wpre = (wv == 0) ? 0 : wsum[wv - 1];
        int incl = carry + wpre + s;
        if (idx < NN) {
            rowp[idx] = incl - v;
            fill[idx] = incl - v;
            invd[idx] = 1.0f / (float)(v > 0 ? v : 1);
        }
        __syncthreads();
        if (tid == 0) chunkbase = carry + wsum[15];
        __syncthreads();
    }
    if (tid == 0) rowp[NN] = NE;
}

__global__ void k_fill(const int* __restrict__ ei, int* __restrict__ fill,
                       int* __restrict__ csrs, int* __restrict__ csre) {
    int e = blockIdx.x * 256 + threadIdx.x;
    if (e < NE) {
        int d = ei[NE + e];
        int p = atomicAdd(&fill[d], 1);
        csrs[p] = ei[e];
        csre[p] = e;
    }
}

// ---------------- W2 split-bf16, transposed to [o][ki] (ki = k*64+i) ----------------
__global__ __launch_bounds__(256) void k_w2f(const float* __restrict__ n2w,
                                             ushort* __restrict__ W2FH,
                                             ushort* __restrict__ W2FL) {
    int lane = threadIdx.x & 63, wvl = threadIdx.x >> 6;
    int ki = blockIdx.x * 4 + wvl;
    float v = n2w[(size_t)ki * 64 + lane];
    ushort hi = f2bf(v);
    ushort lo = f2bf(v - bf2f(hi));
    W2FH[(size_t)lane * 4096 + ki] = hi;
    W2FL[(size_t)lane * 4096 + ki] = lo;
}

// ---------------- edge MLP: hE = relu(edge_attr @ nn1_w + nn1_b) ----------------
__global__ __launch_bounds__(256) void k_edge_h(const float* __restrict__ ea,
                                                const float* __restrict__ w1,
                                                const float* __restrict__ b1,
                                                float* __restrict__ hE) {
    int lane = threadIdx.x & 63, wv = threadIdx.x >> 6;
    int e = blockIdx.x * 4 + wv;
    float av = (lane < FE) ? ea[e * FE + lane] : 0.f;
    float acc = b1[lane];
#pragma unroll
    for (int j = 0; j < FE; ++j) acc += bcast(av, j) * w1[j * 64 + lane];
    hE[e * 64 + lane] = fmaxf(acc, 0.f);
}

// ---------------- lin0 ----------------
__global__ __launch_bounds__(256) void k_lin0(const float* __restrict__ x,
                                              const float* __restrict__ w0,
                                              const float* __restrict__ b0,
                                              float* __restrict__ F) {
    int lane = threadIdx.x & 63, wv = threadIdx.x >> 6;
    int n = blockIdx.x * 4 + wv;
    float xv = (lane < FIN) ? x[n * FIN + lane] : 0.f;
    float acc = b0[lane];
#pragma unroll
    for (int k = 0; k < FIN; ++k) acc += bcast(xv, k) * w0[k * 64 + lane];
    F[n * 64 + lane] = fmaxf(acc, 0.f);
}

// ---------------- fused NNConv via MFMA (split bf16) ----------------
// 16 waves = 16 dst nodes per block. Phase A: G[k][i] in 64 VGPRs (lane=i).
// Then 4 k-chunks: convert->LDS(bf16 hi/lo), MFMA 16x16x32 (A: nodes x ki,
// B: W2F[o][ki]); wave = (otile = wv&3, kq = wv>>2). Reduce over kq via LDS.
__global__ __launch_bounds__(1024) void k_mp(
    const float* __restrict__ F, const float* __restrict__ hE,
    const int* __restrict__ rowp, const int* __restrict__ csrs,
    const int* __restrict__ csre,
    const ushort* __restrict__ W2FH, const ushort* __restrict__ W2FL,
    const float* __restrict__ B2, const float* __restrict__ invd,
    const float* __restrict__ Wroot, const float* __restrict__ broot,
    float* __restrict__ M) {
    __shared__ __align__(16) char smem[70144];
    ushort(*GH)[1032] = (ushort(*)[1032])smem;             // 33024 B
    ushort(*GL)[1032] = (ushort(*)[1032])(smem + 33024);   // 33024 B
    float(*Us)[64] = (float(*)[64])(smem + 66048);         // 4096 B
    float(*Red)[256] = (float(*)[256])smem;                // union over GH
    float(*Agg)[64] = (float(*)[64])(smem + 33024);        // union over GL

    int tid = threadIdx.x, lane = tid & 63, wv = tid >> 6;
    int n = __builtin_amdgcn_readfirstlane(blockIdx.x * 16 + wv);

    // ---- phase A: G[k][i] = sum_e hE[e][k] * F[src][i]; lane = i ----
    float G[64];
#pragma unroll
    for (int k = 0; k < 64; ++k) G[k] = 0.f;
    float usum = 0.f;
    int beg = rowp[n], end = rowp[n + 1];
    for (int p = beg; p < end; ++p) {
        int s = __builtin_amdgcn_readfirstlane(csrs[p]);
        int e = __builtin_amdgcn_readfirstlane(csre[p]);
        float u = F[(size_t)s * 64 + lane];
        const float* h = hE + (size_t)e * 64;  // uniform -> s_load
        usum += u;
#pragma unroll
        for (int k = 0; k < 64; ++k) G[k] = fmaf(h[k], u, G[k]);
    }
    Us[wv][lane] = usum;

    // ---- MFMA phase ----
    f32x4 acc = {0.f, 0.f, 0.f, 0.f};
    int otile = wv & 3, kq = wv >> 2;
    int arow = lane & 15, agrp = lane >> 4;
    int o = otile * 16 + arow;
    const ushort* bhbase = W2FH + (size_t)o * 4096;
    const ushort* blbase = W2FL + (size_t)o * 4096;
#pragma unroll
    for (int c = 0; c < 4; ++c) {
#pragma unroll
        for (int kk = 0; kk < 16; ++kk) {
            float g = G[c * 16 + kk];
            ushort hi = f2bf(g);
            ushort lo = f2bf(g - bf2f(hi));
            GH[wv][kk * 64 + lane] = hi;
            GL[wv][kk * 64 + lane] = lo;
        }
        __syncthreads();
#pragma unroll
        for (int s8 = 0; s8 < 8; ++s8) {
            int ki = (kq * 8 + s8) * 32 + agrp * 8;
            s16x8 ah = *(const s16x8*)&GH[arow][ki];
            s16x8 al = *(const s16x8*)&GL[arow][ki];
            s16x8 bh = *(const s16x8*)&bhbase[c * 1024 + ki];
            s16x8 bl = *(const s16x8*)&blbase[c * 1024 + ki];
            acc = __builtin_amdgcn_mfma_f32_16x16x32_bf16(ah, bh, acc, 0, 0, 0);
            acc = __builtin_amdgcn_mfma_f32_16x16x32_bf16(ah, bl, acc, 0, 0, 0);
            acc = __builtin_amdgcn_mfma_f32_16x16x32_bf16(al, bh, acc, 0, 0, 0);
        }
        __syncthreads();
    }

    // ---- reduce partial D over kq groups ----
    *(f32x4*)&Red[wv][lane * 4] = acc;
    __syncthreads();
    if (wv < 4) {
        int t = wv;
        f32x4 s0 = *(f32x4*)&Red[t][lane * 4];
        f32x4 s1 = *(f32x4*)&Red[t + 4][lane * 4];
        f32x4 s2 = *(f32x4*)&Red[t + 8][lane * 4];
        f32x4 s3 = *(f32x4*)&Red[t + 12][lane * 4];
        f32x4 ss = s0 + s1 + s2 + s3;
        // D[row=node=(lane>>4)*4+r][col=o=t*16+(lane&15)]
#pragma unroll
        for (int r = 0; r < 4; ++r)
            Agg[(lane >> 4) * 4 + r][t * 16 + (lane & 15)] = ss[r];
    }
    __syncthreads();

    // ---- epilogue per node-wave: mean, nn2_b term, root, relu ----
    float b2t = 0.f;
#pragma unroll 8
    for (int i = 0; i < 64; ++i) b2t = fmaf(Us[wv][i], B2[i * 64 + lane], b2t);
    float a = (Agg[wv][lane] + b2t) * invd[n];
    const float* frow = F + (size_t)n * 64;  // uniform -> s_load
    float r = broot[lane];
#pragma unroll
    for (int k = 0; k < 64; ++k) r = fmaf(frow[k], Wroot[k * 64 + lane], r);
    M[(size_t)n * 64 + lane] = fmaxf(a + r, 0.f);
}

// ---------------- GRU: F <- GRU(M, F). k-sliced, weights staged in LDS ----------------
__global__ __launch_bounds__(1024) void k_gru(const float* __restrict__ M_,
                                              float* __restrict__ F,
                                              const float* __restrict__ Wih,
                                              const float* __restrict__ Whh,
                                              const float* __restrict__ bih,
                                              const float* __restrict__ bhh) {
    __shared__ float WI[64 * 192];
    __shared__ float WH[64 * 192];
    __shared__ float Acc[4][16][64];
    int tid = threadIdx.x, lane = tid & 63, wv = tid >> 6;
    for (int idx = tid; idx < 64 * 192 / 4; idx += 1024) {
        ((float4*)WI)[idx] = ((const float4*)Wih)[idx];
        ((float4*)WH)[idx] = ((const float4*)Whh)[idx];
    }
    for (int idx = tid; idx < 4 * 16 * 64; idx += 1024) ((float*)Acc)[idx] = 0.f;
    __syncthreads();

    int n0 = __builtin_amdgcn_readfirstlane(blockIdx.x * 16);
    int k0 = __builtin_amdgcn_readfirstlane(wv * 4);
    float wgt[4][6];
#pragma unroll
    for (int kk = 0; kk < 4; ++kk) {
        int k = k0 + kk;
        wgt[kk][0] = WI[k * 192 + lane];
        wgt[kk][1] = WI[k * 192 + 64 + lane];
        wgt[kk][2] = WI[k * 192 + 128 + lane];
        wgt[kk][3] = WH[k * 192 + lane];
        wgt[kk][4] = WH[k * 192 + 64 + lane];
        wgt[kk][5] = WH[k * 192 + 128 + lane];
    }
    float sr[16], sz[16], gin[16], ghn[16];
#pragma unroll
    for (int i = 0; i < 16; ++i) { sr[i] = sz[i] = gin[i] = ghn[i] = 0.f; }
#pragma unroll
    for (int i = 0; i < 16; ++i) {
        float4 m4 = *(const float4*)&M_[(size_t)(n0 + i) * 64 + k0];  // uniform
        float4 h4 = *(const float4*)&F[(size_t)(n0 + i) * 64 + k0];
        const float* mp = (const float*)&m4;
        const float* hp = (const float*)&h4;
#pragma unroll
        for (int kk = 0; kk < 4; ++kk) {
            float mk = mp[kk], hk = hp[kk];
            sr[i] = fmaf(mk, wgt[kk][0], fmaf(hk, wgt[kk][3], sr[i]));
            sz[i] = fmaf(mk, wgt[kk][1], fmaf(hk, wgt[kk][4], sz[i]));
            gin[i] = fmaf(mk, wgt[kk][2], gin[i]);
            ghn[i] = fmaf(hk, wgt[kk][5], ghn[i]);
        }
    }
#pragma unroll
    for (int i = 0; i < 16; ++i) {
        atomicAdd(&Acc[0][i][lane], sr[i]);
        atomicAdd(&Acc[1][i][lane], sz[i]);
        atomicAdd(&Acc[2][i][lane], gin[i]);
        atomicAdd(&Acc[3][i][lane], ghn[i]);
    }
    __syncthreads();

    int n = n0 + wv;
    float h = F[(size_t)n * 64 + lane];
    float s_r = Acc[0][wv][lane] + bih[lane] + bhh[lane];
    float s_z = Acc[1][wv][lane] + bih[64 + lane] + bhh[64 + lane];
    float gi_n = Acc[2][wv][lane] + bih[128 + lane];
    float gh_n = Acc[3][wv][lane] + bhh[128 + lane];
    float rr = 1.f / (1.f + __expf(-s_r));
    float zz = 1.f / (1.f + __expf(-s_z));
    float ng = tanhf(gi_n + rr * gh_n);
    F[(size_t)n * 64 + lane] = (1.f - zz) * ng + zz * h;
}

// ---------------- final ----------------
__global__ __launch_bounds__(256) void k_final(const float* __restrict__ F,
                                               const float* __restrict__ W1,
                                               const float* __restrict__ b1f,
                                               const float* __restrict__ W2l,
                                               const float* __restrict__ b2f,
                                               float* __restrict__ out) {
    int lane = threadIdx.x & 63, wv = threadIdx.x >> 6;
    int n = blockIdx.x * 4 + wv;
    float fv = F[n * 64 + lane];
    float acc = b1f[lane];
#pragma unroll
    for (int k = 0; k < 64; ++k) acc += bcast(fv, k) * W1[k * 64 + lane];
    acc = fmaxf(acc, 0.f);
    float p = acc * W2l[lane];
#pragma unroll
    for (int off = 32; off; off >>= 1) p += __shfl_xor(p, off, 64);
    if (lane == 0) out[n] = p + b2f[0];
}

extern "C" void kernel_launch(void* const* d_in, const int* in_sizes, int n_in,
                              void* d_out, int out_size, void* d_ws, size_t ws_size,
                              hipStream_t stream) {
    const float* x = (const float*)d_in[0];
    const int* ei = (const int*)d_in[1];
    const float* ea = (const float*)d_in[2];
    const float* l0w = (const float*)d_in[3];
    const float* l0b = (const float*)d_in[4];
    const float* n1w = (const float*)d_in[5];
    const float* n1b = (const float*)d_in[6];
    const float* n2w = (const float*)d_in[7];
    const float* n2b = (const float*)d_in[8];
    const float* cr = (const float*)d_in[9];
    const float* cb = (const float*)d_in[10];
    const float* wih = (const float*)d_in[11];
    const float* whh = (const float*)d_in[12];
    const float* bih = (const float*)d_in[13];
    const float* bhh = (const float*)d_in[14];
    const float* l1w = (const float*)d_in[15];
    const float* l1b = (const float*)d_in[16];
    const float* l2w = (const float*)d_in[17];
    const float* l2b = (const float*)d_in[18];

    char* w = (char*)d_ws;
    size_t off = 0;
    float* F = (float*)(w + off); off += (size_t)NN * 64 * 4;
    float* M = (float*)(w + off); off += (size_t)NN * 64 * 4;
    float* hE = (float*)(w + off); off += (size_t)NE * 64 * 4;
    ushort* W2FH = (ushort*)(w + off); off += (size_t)64 * 4096 * 2;
    ushort* W2FL = (ushort*)(w + off); off += (size_t)64 * 4096 * 2;
    float* invd = (float*)(w + off); off += (size_t)NN * 4;
    int* deg = (int*)(w + off); off += (size_t)NN * 4;
    int* rowp = (int*)(w + off); off += (size_t)(NN + 1) * 4 + 252; off &= ~(size_t)255;
    int* fill = (int*)(w + off); off += (size_t)NN * 4;
    int* csrs = (int*)(w + off); off += (size_t)NE * 4;
    int* csre = (int*)(w + off); off += (size_t)NE * 4;

    hipMemsetAsync(deg, 0, NN * 4, stream);
    k_count<<<(NE + 255) / 256, 256, 0, stream>>>(ei, deg);
    k_scan<<<1, 1024, 0, stream>>>(deg, rowp, fill, invd);
    k_fill<<<(NE + 255) / 256, 256, 0, stream>>>(ei, fill, csrs, csre);
    k_w2f<<<1024, 256, 0, stream>>>(n2w, W2FH, W2FL);
    k_edge_h<<<NE / 4, 256, 0, stream>>>(ea, n1w, n1b, hE);
    k_lin0<<<NN / 4, 256, 0, stream>>>(x, l0w, l0b, F);
    for (int it = 0; it < 3; ++it) {
        k_mp<<<NN / 16, 1024, 0, stream>>>(F, hE, rowp, csrs, csre, W2FH, W2FL,
                                           n2b, invd, cr, cb, M);
        k_gru<<<NN / 16, 1024, 0, stream>>>(M, F, wih, whh, bih, bhh);
    }
    k_final<<<NN / 4, 256, 0, stream>>>(F, l1w, l1b, l2w, l2b, (float*)d_out);
}

// Round 3
// 636.092 us; speedup vs baseline: 1.9530x; 1.9530x over previous
//
#include <hip/hip_runtime.h>
#include <hip/hip_bf16.h>

#define NN 10000
#define NE 50000
#define FIN 40
#define FE 10
// L = 64

typedef float f32x4 __attribute__((ext_vector_type(4)));
typedef short s16x8 __attribute__((ext_vector_type(8)));

__device__ __forceinline__ float bcast(float v, int lane) {
    return __uint_as_float(__builtin_amdgcn_readlane(__float_as_uint(v), lane));
}
__device__ __forceinline__ ushort f2bf(float f) {
    uint u = __float_as_uint(f);
    uint r = (u + 0x7FFFu + ((u >> 16) & 1u)) >> 16;
    return (ushort)r;
}
__device__ __forceinline__ float bf2f(ushort h) {
    return __uint_as_float(((uint)h) << 16);
}

// ---------------- CSR build ----------------
__global__ void k_count(const int* __restrict__ ei, int* __restrict__ deg) {
    int e = blockIdx.x * 256 + threadIdx.x;
    if (e < NE) atomicAdd(&deg[ei[NE + e]], 1);
}

__global__ __launch_bounds__(1024) void k_scan(const int* __restrict__ deg,
                                               int* __restrict__ rowp,
                                               int* __restrict__ fill,
                                               float* __restrict__ invd) {
    __shared__ int wsum[16];
    __shared__ int chunkbase;
    int tid = threadIdx.x, lane = tid & 63, wv = tid >> 6;
    if (tid == 0) chunkbase = 0;
    __syncthreads();
    for (int base = 0; base < NN; base += 1024) {
        int idx = base + tid;
        int v = (idx < NN) ? deg[idx] : 0;
        int s = v;
#pragma unroll
        for (int off = 1; off < 64; off <<= 1) {
            int t = __shfl_up(s, off, 64);
            if (lane >= off) s += t;
        }
        if (lane == 63) wsum[wv] = s;
        __syncthreads();
        int carry = chunkbase;
        if (wv == 0 && lane < 16) {
            int x = wsum[lane];
#pragma unroll
            for (int off = 1; off < 16; off <<= 1) {
                int t = __shfl_up(x, off, 64);
                if (lane >= off) x += t;
            }
            wsum[lane] = x;  // inclusive over waves
        }
        __syncthreads();
        int wpre = (wv == 0) ? 0 : wsum[wv - 1];
        int incl = carry + wpre + s;
        if (idx < NN) {
            rowp[idx] = incl - v;
            fill[idx] = incl - v;
            invd[idx] = 1.0f / (float)(v > 0 ? v : 1);
        }
        __syncthreads();
        if (tid == 0) chunkbase = carry + wsum[15];
        __syncthreads();
    }
    if (tid == 0) rowp[NN] = NE;
}

__global__ void k_fill(const int* __restrict__ ei, int* __restrict__ fill,
                       int* __restrict__ csrs, int* __restrict__ csre) {
    int e = blockIdx.x * 256 + threadIdx.x;
    if (e < NE) {
        int d = ei[NE + e];
        int p = atomicAdd(&fill[d], 1);
        csrs[p] = ei[e];
        csre[p] = e;
    }
}

// ---------------- W2 split-bf16, transposed to [o][ki] (ki = k*64+i) ----------------
__global__ __launch_bounds__(256) void k_w2f(const float* __restrict__ n2w,
                                             ushort* __restrict__ W2FH,
                                             ushort* __restrict__ W2FL) {
    int lane = threadIdx.x & 63, wvl = threadIdx.x >> 6;
    int ki = blockIdx.x * 4 + wvl;
    float v = n2w[(size_t)ki * 64 + lane];
    ushort hi = f2bf(v);
    ushort lo = f2bf(v - bf2f(hi));
    W2FH[(size_t)lane * 4096 + ki] = hi;
    W2FL[(size_t)lane * 4096 + ki] = lo;
}

// ---------------- edge MLP: hE = relu(edge_attr @ nn1_w + nn1_b) ----------------
__global__ __launch_bounds__(256) void k_edge_h(const float* __restrict__ ea,
                                                const float* __restrict__ w1,
                                                const float* __restrict__ b1,
                                                float* __restrict__ hE) {
    int lane = threadIdx.x & 63, wv = threadIdx.x >> 6;
    int e = blockIdx.x * 4 + wv;
    float av = (lane < FE) ? ea[e * FE + lane] : 0.f;
    float acc = b1[lane];
#pragma unroll
    for (int j = 0; j < FE; ++j) acc += bcast(av, j) * w1[j * 64 + lane];
    hE[e * 64 + lane] = fmaxf(acc, 0.f);
}

// ---------------- lin0 ----------------
__global__ __launch_bounds__(256) void k_lin0(const float* __restrict__ x,
                                              const float* __restrict__ w0,
                                              const float* __restrict__ b0,
                                              float* __restrict__ F) {
    int lane = threadIdx.x & 63, wv = threadIdx.x >> 6;
    int n = blockIdx.x * 4 + wv;
    float xv = (lane < FIN) ? x[n * FIN + lane] : 0.f;
    float acc = b0[lane];
#pragma unroll
    for (int k = 0; k < FIN; ++k) acc += bcast(xv, k) * w0[k * 64 + lane];
    F[n * 64 + lane] = fmaxf(acc, 0.f);
}

// ---------------- fused NNConv + GRU via MFMA (split bf16) ----------------
// 16 waves = 16 dst nodes per block. Phase A: G[k][i] in 64 VGPRs (lane=i).
// 4 k-chunks: convert->LDS(bf16 hi/lo), MFMA 16x16x32; wave=(otile=wv&3,
// kq=wv>>2). Reduce over kq via LDS. Epilogue: mean + root + relu -> m,
// then single-step GRU, writing h' to Fout (ping-pong, no race with F reads).
__global__ __launch_bounds__(1024) void k_mp(
    const float* __restrict__ F, const float* __restrict__ hE,
    const int* __restrict__ rowp, const int* __restrict__ csrs,
    const int* __restrict__ csre,
    const ushort* __restrict__ W2FH, const ushort* __restrict__ W2FL,
    const float* __restrict__ B2, const float* __restrict__ invd,
    const float* __restrict__ Wroot, const float* __restrict__ broot,
    const float* __restrict__ Wih, const float* __restrict__ Whh,
    const float* __restrict__ bih, const float* __restrict__ bhh,
    float* __restrict__ Fout) {
    __shared__ __align__(16) char smem[70144];
    ushort(*GH)[1032] = (ushort(*)[1032])smem;             // 33024 B
    ushort(*GL)[1032] = (ushort(*)[1032])(smem + 33024);   // 33024 B
    float(*Us)[64] = (float(*)[64])(smem + 66048);         // 4096 B
    float(*Red)[256] = (float(*)[256])smem;                // union over GH
    float(*Agg)[64] = (float(*)[64])(smem + 33024);        // union over GL

    int tid = threadIdx.x, lane = tid & 63, wv = tid >> 6;
    int n = __builtin_amdgcn_readfirstlane(blockIdx.x * 16 + wv);

    // ---- phase A: G[k][i] = sum_e hE[e][k] * F[src][i]; lane = i ----
    float G[64];
#pragma unroll
    for (int k = 0; k < 64; ++k) G[k] = 0.f;
    float usum = 0.f;
    int beg = rowp[n], end = rowp[n + 1];
    for (int p = beg; p < end; ++p) {
        int s = __builtin_amdgcn_readfirstlane(csrs[p]);
        int e = __builtin_amdgcn_readfirstlane(csre[p]);
        float u = F[(size_t)s * 64 + lane];
        const float* h = hE + (size_t)e * 64;  // uniform -> s_load
        usum += u;
#pragma unroll
        for (int k = 0; k < 64; ++k) G[k] = fmaf(h[k], u, G[k]);
    }
    Us[wv][lane] = usum;

    // ---- MFMA phase ----
    f32x4 acc = {0.f, 0.f, 0.f, 0.f};
    int otile = wv & 3, kq = wv >> 2;
    int arow = lane & 15, agrp = lane >> 4;
    int o = otile * 16 + arow;
    const ushort* bhbase = W2FH + (size_t)o * 4096;
    const ushort* blbase = W2FL + (size_t)o * 4096;
#pragma unroll
    for (int c = 0; c < 4; ++c) {
#pragma unroll
        for (int kk = 0; kk < 16; ++kk) {
            float g = G[c * 16 + kk];
            ushort hi = f2bf(g);
            ushort lo = f2bf(g - bf2f(hi));
            GH[wv][kk * 64 + lane] = hi;
            GL[wv][kk * 64 + lane] = lo;
        }
        __syncthreads();
#pragma unroll
        for (int s8 = 0; s8 < 8; ++s8) {
            int ki = (kq * 8 + s8) * 32 + agrp * 8;
            s16x8 ah = *(const s16x8*)&GH[arow][ki];
            s16x8 al = *(const s16x8*)&GL[arow][ki];
            s16x8 bh = *(const s16x8*)&bhbase[c * 1024 + ki];
            s16x8 bl = *(const s16x8*)&blbase[c * 1024 + ki];
            acc = __builtin_amdgcn_mfma_f32_16x16x32_bf16(ah, bh, acc, 0, 0, 0);
            acc = __builtin_amdgcn_mfma_f32_16x16x32_bf16(ah, bl, acc, 0, 0, 0);
            acc = __builtin_amdgcn_mfma_f32_16x16x32_bf16(al, bh, acc, 0, 0, 0);
        }
        __syncthreads();
    }

    // ---- reduce partial D over kq groups ----
    *(f32x4*)&Red[wv][lane * 4] = acc;
    __syncthreads();
    if (wv < 4) {
        int t = wv;
        f32x4 s0 = *(f32x4*)&Red[t][lane * 4];
        f32x4 s1 = *(f32x4*)&Red[t + 4][lane * 4];
        f32x4 s2 = *(f32x4*)&Red[t + 8][lane * 4];
        f32x4 s3 = *(f32x4*)&Red[t + 12][lane * 4];
        f32x4 ss = s0 + s1 + s2 + s3;
        // D[row=node=(lane>>4)*4+r][col=o=t*16+(lane&15)]
#pragma unroll
        for (int r = 0; r < 4; ++r)
            Agg[(lane >> 4) * 4 + r][t * 16 + (lane & 15)] = ss[r];
    }
    __syncthreads();

    // ---- epilogue per node-wave: mean + nn2_b + root -> relu -> m ----
    float b2t = 0.f;
#pragma unroll 8
    for (int i = 0; i < 64; ++i) b2t = fmaf(Us[wv][i], B2[i * 64 + lane], b2t);
    float a = (Agg[wv][lane] + b2t) * invd[n];
    const float* frow = F + (size_t)n * 64;  // uniform -> s_load
    float r = broot[lane];
#pragma unroll
    for (int k = 0; k < 64; ++k) r = fmaf(frow[k], Wroot[k * 64 + lane], r);
    float m = fmaxf(a + r, 0.f);

    // ---- fused single-step GRU: h' = (1-z)*ng + z*h ----
    float h = F[(size_t)n * 64 + lane];
    float sr = bih[lane] + bhh[lane];
    float sz = bih[64 + lane] + bhh[64 + lane];
    float gin = bih[128 + lane];
    float ghn = bhh[128 + lane];
#pragma unroll
    for (int k = 0; k < 64; ++k) {
        float mk = bcast(m, k), hk = bcast(h, k);
        const float* wi = &Wih[k * 192];
        const float* wh = &Whh[k * 192];
        sr = fmaf(mk, wi[lane], fmaf(hk, wh[lane], sr));
        sz = fmaf(mk, wi[64 + lane], fmaf(hk, wh[64 + lane], sz));
        gin = fmaf(mk, wi[128 + lane], gin);
        ghn = fmaf(hk, wh[128 + lane], ghn);
    }
    float rr = 1.f / (1.f + __expf(-sr));
    float zz = 1.f / (1.f + __expf(-sz));
    float ng = tanhf(gin + rr * ghn);
    Fout[(size_t)n * 64 + lane] = (1.f - zz) * ng + zz * h;
}

// ---------------- final ----------------
__global__ __launch_bounds__(256) void k_final(const float* __restrict__ F,
                                               const float* __restrict__ W1,
                                               const float* __restrict__ b1f,
                                               const float* __restrict__ W2l,
                                               const float* __restrict__ b2f,
                                               float* __restrict__ out) {
    int lane = threadIdx.x & 63, wv = threadIdx.x >> 6;
    int n = blockIdx.x * 4 + wv;
    float fv = F[n * 64 + lane];
    float acc = b1f[lane];
#pragma unroll
    for (int k = 0; k < 64; ++k) acc += bcast(fv, k) * W1[k * 64 + lane];
    acc = fmaxf(acc, 0.f);
    float p = acc * W2l[lane];
#pragma unroll
    for (int off = 32; off; off >>= 1) p += __shfl_xor(p, off, 64);
    if (lane == 0) out[n] = p + b2f[0];
}

extern "C" void kernel_launch(void* const* d_in, const int* in_sizes, int n_in,
                              void* d_out, int out_size, void* d_ws, size_t ws_size,
                              hipStream_t stream) {
    const float* x = (const float*)d_in[0];
    const int* ei = (const int*)d_in[1];
    const float* ea = (const float*)d_in[2];
    const float* l0w = (const float*)d_in[3];
    const float* l0b = (const float*)d_in[4];
    const float* n1w = (const float*)d_in[5];
    const float* n1b = (const float*)d_in[6];
    const float* n2w = (const float*)d_in[7];
    const float* n2b = (const float*)d_in[8];
    const float* cr = (const float*)d_in[9];
    const float* cb = (const float*)d_in[10];
    const float* wih = (const float*)d_in[11];
    const float* whh = (const float*)d_in[12];
    const float* bih = (const float*)d_in[13];
    const float* bhh = (const float*)d_in[14];
    const float* l1w = (const float*)d_in[15];
    const float* l1b = (const float*)d_in[16];
    const float* l2w = (const float*)d_in[17];
    const float* l2b = (const float*)d_in[18];

    char* w = (char*)d_ws;
    size_t off = 0;
    float* F0 = (float*)(w + off); off += (size_t)NN * 64 * 4;
    float* F1 = (float*)(w + off); off += (size_t)NN * 64 * 4;
    float* hE = (float*)(w + off); off += (size_t)NE * 64 * 4;
    ushort* W2FH = (ushort*)(w + off); off += (size_t)64 * 4096 * 2;
    ushort* W2FL = (ushort*)(w + off); off += (size_t)64 * 4096 * 2;
    float* invd = (float*)(w + off); off += (size_t)NN * 4;
    int* deg = (int*)(w + off); off += (size_t)NN * 4;
    int* rowp = (int*)(w + off); off += (size_t)(NN + 1) * 4 + 252; off &= ~(size_t)255;
    int* fill = (int*)(w + off); off += (size_t)NN * 4;
    int* csrs = (int*)(w + off); off += (size_t)NE * 4;
    int* csre = (int*)(w + off); off += (size_t)NE * 4;

    hipMemsetAsync(deg, 0, NN * 4, stream);
    k_count<<<(NE + 255) / 256, 256, 0, stream>>>(ei, deg);
    k_scan<<<1, 1024, 0, stream>>>(deg, rowp, fill, invd);
    k_fill<<<(NE + 255) / 256, 256, 0, stream>>>(ei, fill, csrs, csre);
    k_w2f<<<1024, 256, 0, stream>>>(n2w, W2FH, W2FL);
    k_edge_h<<<NE / 4, 256, 0, stream>>>(ea, n1w, n1b, hE);
    k_lin0<<<NN / 4, 256, 0, stream>>>(x, l0w, l0b, F0);
    float* Fcur = F0;
    float* Fnxt = F1;
    for (int it = 0; it < 3; ++it) {
        k_mp<<<NN / 16, 1024, 0, stream>>>(Fcur, hE, rowp, csrs, csre, W2FH,
                                           W2FL, n2b, invd, cr, cb, wih, whh,
                                           bih, bhh, Fnxt);
        float* t = Fcur; Fcur = Fnxt; Fnxt = t;
    }
    k_final<<<NN / 4, 256, 0, stream>>>(Fcur, l1w, l1b, l2w, l2b, (float*)d_out);
}